// Round 1
// baseline (256.764 us; speedup 1.0000x reference)
//
#include <hip/hip_runtime.h>

// out[h1,w1,c1,h2,w2,c2] =
//   gamma^(|h1-h2|+|w1-w2|+|c1-c2|) * (1 + spec_pe[c1,c2]*mean[h1,w1,c1]) * decay[c1]
// mean[h1,w1,c1] = Sh[h1]*Sh[w1]*Sc[c1] / 8192   (separable Manhattan mask mean)
// H=W=32, C=8 (=num_heads=head_dim), output 67,108,864 fp32 = 256 MiB (write-bound).

constexpr int TOTAL_F4 = 16777216;  // 67108864 / 4

__global__ __launch_bounds__(256) void manhattan_relpos_kernel(
    const float* __restrict__ decay,    // 8 elems
    const float* __restrict__ spec_pe,  // 64 elems
    float* __restrict__ out)            // 67108864 floats
{
    __shared__ float powtab[72];  // gamma^d, d in [0,69]
    __shared__ float Sh[32];      // sum_j gamma^|h-j|, j in [0,32)
    __shared__ float meanC[8];    // (sum_c2 gamma^|c1-c2|) / 8192
    __shared__ float A[64];       // gamma^|c1-c2| * decay[c1]
    __shared__ float SP[64];      // spec_pe[c1*8+c2]

    const int tid = threadIdx.x;

    // --- tiny per-block table setup (amortized over 8 f4-stores/thread) ---
    if (tid < 72) {
        // log2(0.9) = -0.15200309344504997
        powtab[tid] = exp2f((float)tid * -0.15200309344504997f);
    }
    __syncthreads();
    if (tid < 32) {
        float s = 0.0f;
        #pragma unroll
        for (int j = 0; j < 32; ++j) s += powtab[abs(tid - j)];
        Sh[tid] = s;
    } else if (tid < 40) {
        const int c1 = tid - 32;
        float s = 0.0f;
        #pragma unroll
        for (int j = 0; j < 8; ++j) s += powtab[abs(c1 - j)];
        meanC[c1] = s * (1.0f / 8192.0f);
    } else if (tid >= 64 && tid < 128) {
        const int i = tid - 64;
        const int c1 = i >> 3, c2 = i & 7;
        A[i]  = powtab[abs(c1 - c2)] * decay[c1];
        SP[i] = spec_pe[i];
    }
    __syncthreads();

    // float4 index bits: 0 = c2-half, 1..5 = w2, 6..10 = h2, 11..13 = c1,
    //                    14..18 = w1, 19..23 = h1
    const int stride = gridDim.x * blockDim.x;  // 8192*256 = 2,097,152
    for (int idx = blockIdx.x * blockDim.x + tid; idx < TOTAL_F4; idx += stride) {
        const int half = idx & 1;
        const int w2 = (idx >> 1)  & 31;
        const int h2 = (idx >> 6)  & 31;
        const int c1 = (idx >> 11) & 7;
        const int w1 = (idx >> 14) & 31;
        const int h1 = (idx >> 19) & 31;

        const float p = powtab[abs(h1 - h2) + abs(w1 - w2)];
        const float m = Sh[h1] * Sh[w1] * meanC[c1];
        const int cbase = (c1 << 3) + (half << 2);

        float4 v;
        v.x = p * A[cbase + 0] * fmaf(SP[cbase + 0], m, 1.0f);
        v.y = p * A[cbase + 1] * fmaf(SP[cbase + 1], m, 1.0f);
        v.z = p * A[cbase + 2] * fmaf(SP[cbase + 2], m, 1.0f);
        v.w = p * A[cbase + 3] * fmaf(SP[cbase + 3], m, 1.0f);
        reinterpret_cast<float4*>(out)[idx] = v;
    }
}

extern "C" void kernel_launch(void* const* d_in, const int* in_sizes, int n_in,
                              void* d_out, int out_size, void* d_ws, size_t ws_size,
                              hipStream_t stream) {
    // d_in[0] = x (unused by the math — only shape/dtype matter)
    const float* decay   = (const float*)d_in[1];
    const float* spec_pe = (const float*)d_in[2];
    float* out = (float*)d_out;

    dim3 grid(8192), block(256);
    manhattan_relpos_kernel<<<grid, block, 0, stream>>>(decay, spec_pe, out);
}